// Round 5
// baseline (139.755 us; speedup 1.0000x reference)
//
#include <hip/hip_runtime.h>

#define DD 8
#define HW 16384
#define KK 256
#define NPIX 524288
#define PPT 4                          // pixels per thread
#define NBLK 512                       // 1024 px per block

#define Y_OFF    4194304UL             // B*D*H*W
#define REP_OFF  4718592UL             // + B*H*W
#define LOSS_OFF 138936320UL           // + B*H*W*K

typedef float f4 __attribute__((ext_vector_type(4)));

// ---------------- fused: argmax + pipelined one-hot streaming ----------------
__global__ __launch_bounds__(256) void vq_fused_kernel(
    const float* __restrict__ q, const float* __restrict__ cb,
    float* __restrict__ emb, float* __restrict__ yf, float* __restrict__ rep,
    int* __restrict__ hist, float* __restrict__ partial)
{
    __shared__ float sc2[KK];
    __shared__ int   shist[KK];
    __shared__ float swred[4];

    const int tid  = threadIdx.x;
    const int wid  = tid >> 6;
    const int lane = tid & 63;

    shist[tid] = 0;
    {   // ||c||^2 per block (same formula as reference np.sum expansion)
        const f4 c01 = *(const f4*)(cb + tid*8);
        const f4 c23 = *(const f4*)(cb + tid*8 + 4);
        sc2[tid] = ((c01.x*c01.x + c01.y*c01.y) + (c01.z*c01.z + c01.w*c01.w))
                 + ((c23.x*c23.x + c23.y*c23.y) + (c23.z*c23.z + c23.w*c23.w));
    }
    __syncthreads();

    const int blockBase = blockIdx.x << 10;      // 1024 consecutive pixels
    const int b   = blockBase >> 14;             // image index (16 blocks/image)
    const int hwB = blockBase & (HW - 1);
    const float* qb = q + (size_t)b * (DD*HW);
    float* eb = emb + (size_t)b * (DD*HW);

    float err = 0.f;
    float xsbuf[2][DD];

    // prologue: load pixel-group 0
#pragma unroll
    for (int d = 0; d < DD; ++d) xsbuf[0][d] = qb[d*HW + hwB + tid];

#pragma unroll
    for (int i = 0; i < PPT; ++i) {
        const int cur = i & 1, nxt = cur ^ 1;    // compile-time after unroll
        const int hw = hwB + (i << 8) + tid;

        float xs[DD];
#pragma unroll
        for (int d = 0; d < DD; ++d) xs[d] = xsbuf[cur][d];
        const float xn = ((xs[0]*xs[0] + xs[1]*xs[1]) + (xs[2]*xs[2] + xs[3]*xs[3]))
                       + ((xs[4]*xs[4] + xs[5]*xs[5]) + (xs[6]*xs[6] + xs[7]*xs[7]));

        // t = (x2 - 2xc) + c2 with strict <  ==  reference -0.5*t with strict >
        float best = 3.4e38f;
        int   yb   = 0;
#pragma unroll 4
        for (int k = 0; k < KK; ++k) {
            const f4 c01 = *(const f4*)(cb + (k << 3));      // lane-invariant -> s_load
            const f4 c23 = *(const f4*)(cb + (k << 3) + 4);
            const float c2k = sc2[k];                        // LDS broadcast
            float dot = 0.f;
            dot = fmaf(xs[0], c01.x, dot);
            dot = fmaf(xs[1], c01.y, dot);
            dot = fmaf(xs[2], c01.z, dot);
            dot = fmaf(xs[3], c01.w, dot);
            dot = fmaf(xs[4], c23.x, dot);
            dot = fmaf(xs[5], c23.y, dot);
            dot = fmaf(xs[6], c23.z, dot);
            dot = fmaf(xs[7], c23.w, dot);
            const float t = (xn - 2.0f*dot) + c2k;
            if (t < best) { best = t; yb = k; }   // first index wins ties
        }

        // issue next group's q loads BEFORE the store burst so the next
        // k-loop's vmcnt wait doesn't drain the store queue
        if (i + 1 < PPT) {
            const int hw2 = hwB + ((i + 1) << 8) + tid;
#pragma unroll
            for (int d = 0; d < DD; ++d) xsbuf[nxt][d] = qb[d*HW + hw2];
        }

        // per-pixel outputs: emb, err, y, hist
        {
            const f4 cy01 = *(const f4*)(cb + (yb << 3));
            const f4 cy23 = *(const f4*)(cb + (yb << 3) + 4);
            const float cyv[DD] = {cy01.x, cy01.y, cy01.z, cy01.w,
                                   cy23.x, cy23.y, cy23.z, cy23.w};
#pragma unroll
            for (int d = 0; d < DD; ++d) {
                eb[d*HW + hw] = cyv[d];
                const float dd = cyv[d] - xs[d];
                err = fmaf(dd, dd, err);
            }
        }
        yf[blockBase + (i << 8) + tid] = (float)yb;
        atomicAdd(&shist[yb], 1);

        // stream this wave's 64 one-hot rows (no barrier needed: y via shfl)
        {
            const int rowPix = blockBase + (i << 8) + (wid << 6);
            f4* repb = (f4*)rep + (size_t)rowPix * 64 + lane;
            const int b4 = lane << 2;
            for (int r = 0; r < 64; ++r) {
                const int y = __shfl(yb, r, 64);     // wave-uniform broadcast
                f4 v;
                v.x = (y == b4    ) ? 1.0f : 0.0f;
                v.y = (y == b4 + 1) ? 1.0f : 0.0f;
                v.z = (y == b4 + 2) ? 1.0f : 0.0f;
                v.w = (y == b4 + 3) ? 1.0f : 0.0f;
                __builtin_nontemporal_store(v, repb + (size_t)r * 64);
            }
        }
    }

    // deterministic block reduction of err
#pragma unroll
    for (int off = 32; off; off >>= 1)
        err += __shfl_down(err, off, 64);
    if (lane == 0) swred[wid] = err;
    __syncthreads();
    if (tid == 0)
        partial[blockIdx.x] = (swred[0] + swred[1]) + (swred[2] + swred[3]);
    atomicAdd(&hist[tid], shist[tid]);   // shist complete after barrier above
}

// ---------------- finalize scalars ----------------
__global__ __launch_bounds__(256) void vq_final_kernel(
    const float* __restrict__ partial, const int* __restrict__ hist,
    float* __restrict__ outp)
{
    const int tid = threadIdx.x;
    __shared__ double sred[4];
    __shared__ double shy[4];

    double s = (double)partial[tid] + (double)partial[tid + 256];
#pragma unroll
    for (int off = 32; off; off >>= 1)
        s += __shfl_down(s, off, 64);
    if ((tid & 63) == 0) sred[tid >> 6] = s;

    float c  = (float)hist[tid];
    float py = c * (1.0f / 524288.0f);
    double ht = (double)(py * log2f(py + 1e-10f));
#pragma unroll
    for (int off = 32; off; off >>= 1)
        ht += __shfl_down(ht, off, 64);
    if ((tid & 63) == 0) shy[tid >> 6] = ht;
    __syncthreads();

    if (tid == 0) {
        double S  = (sred[0] + sred[1]) + (sred[2] + sred[3]);
        double Hy = (shy[0]  + shy[1])  + (shy[2]  + shy[3]);
        // loss = 0.5*(0.25*S/4096 + S/4096) = 0.625 * S / 4096
        outp[0] = (float)(0.625 * S / 4096.0);
        outp[1] = (float)(-Hy);
        outp[2] = 0.0f;
    }
}

extern "C" void kernel_launch(void* const* d_in, const int* in_sizes, int n_in,
                              void* d_out, int out_size, void* d_ws, size_t ws_size,
                              hipStream_t stream)
{
    const float* q  = (const float*)d_in[0];
    const float* cb = (const float*)d_in[1];
    float* out = (float*)d_out;

    float* emb = out;                     // [B,D,H,W]
    float* yf  = out + Y_OFF;             // [B,H,W] as float
    float* rep = out + REP_OFF;           // [B,H,W,K]
    float* sc  = out + LOSS_OFF;          // loss, Hy, Hyx

    float* w       = (float*)d_ws;
    int*   hist    = (int*)w;             // 256 ints
    float* partial = w + 256;             // 512 floats

    hipMemsetAsync(hist, 0, 1024, stream);   // zero hist
    vq_fused_kernel<<<NBLK, 256, 0, stream>>>(q, cb, emb, yf, rep, hist, partial);
    vq_final_kernel<<<1, 256, 0, stream>>>(partial, hist, sc);
}